// Round 5
// baseline (188.615 us; speedup 1.0000x reference)
//
#include <hip/hip_runtime.h>

// PointNet 3-NN feature interpolation, v4.
// pack_points: xyz1 -> packed {2x, 2y, 2z, norm} float4 (L2-resident, 1 MB).
// knn3_main  : query-per-thread, direct uniform-address reads of packed pts,
//              self-thresholded insert (if d < running d2), per-chunk partials.
// knn3_merge : merge per-chunk top-3s (exact, ascending order), weights.
// interp     : per-(b,d) row staged in LDS, gather+weighted-sum.

constexpr int QT = 256;  // queries per block in knn3_main
constexpr int NCHUNK = 8;

__device__ __forceinline__ void insert3b(float& d0, float& d1, float& d2,
                                         int& i0, int& i1, int& i2,
                                         float d, int n) {
    bool c0 = d < d0, c1 = d < d1, c2 = d < d2;
    float nd2 = c1 ? d1 : (c2 ? d : d2);
    int   ni2 = c1 ? i1 : (c2 ? n : i2);
    float nd1 = c0 ? d0 : (c1 ? d : d1);
    int   ni1 = c0 ? i0 : (c1 ? n : i1);
    float nd0 = c0 ? d  : d0;
    int   ni0 = c0 ? n  : i0;
    d0 = nd0; d1 = nd1; d2 = nd2;
    i0 = ni0; i1 = ni1; i2 = ni2;
}

// insert knowing d < d2 (branch guard already established)
__device__ __forceinline__ void insert3_hit(float& d0, float& d1, float& d2,
                                            int& i0, int& i1, int& i2,
                                            float d, int n) {
    bool c0 = d < d0, c1 = d < d1;
    float nd0 = c0 ? d  : d0;
    float nd1 = c0 ? d0 : (c1 ? d : d1);
    float nd2 = c1 ? d1 : d;
    int   ni0 = c0 ? n  : i0;
    int   ni1 = c0 ? i0 : (c1 ? n : i1);
    int   ni2 = c1 ? i1 : n;
    d0 = nd0; d1 = nd1; d2 = nd2;
    i0 = ni0; i1 = ni1; i2 = ni2;
}

// pk[b*N + n] = {2x, 2y, 2z, (x*x + y*y) + z*z}
// 2x is exact (pow2 scale); (qx*2x + qy*2y) + qz*2z rounds bit-identically
// to 2*((qx*x + qy*y) + qz*z).
__global__ __launch_bounds__(256)
void pack_points(const float* __restrict__ xyz1, float4* __restrict__ pk,
                 int B, int N)
{
#pragma clang fp contract(off)
    int t = blockIdx.x * 256 + threadIdx.x;
    if (t >= B * N) return;
    int b = t / N, n = t - b * N;
    const float* __restrict__ bx = xyz1 + (size_t)b * 3 * N;
    float x = bx[n], y = bx[N + n], z = bx[2 * N + n];
    pk[t] = make_float4(x + x, y + y, z + z, (x * x + y * y) + z * z);
}

__global__ __launch_bounds__(256)
void knn3_main(const float4* __restrict__ pk, const float* __restrict__ xyz2,
               int B, int N, int S, int cs, int BS,
               float* __restrict__ pd0, float* __restrict__ pd1,
               float* __restrict__ pd2,
               int* __restrict__ pi0, int* __restrict__ pi1,
               int* __restrict__ pi2)
{
#pragma clang fp contract(off)
    const int q  = blockIdx.x * QT + threadIdx.x;
    const int c  = blockIdx.y;
    const int b  = q / S;                 // QT | S
    const int s  = q - b * S;
    const int n0 = c * cs;

    const float* __restrict__ q2p = xyz2 + (size_t)b * 3 * S;
    const float qx = q2p[s];
    const float qy = q2p[S + s];
    const float qz = q2p[2 * S + s];
    const float qss = (qx * qx + qy * qy) + qz * qz;

    const float4* __restrict__ pc = pk + (size_t)b * N + n0;  // uniform base

    float d0 = 3.4e38f, d1 = 3.4e38f, d2 = 3.4e38f;
    int   i0 = 0, i1 = 0, i2 = 0;

#pragma unroll 4
    for (int k = 0; k < cs; ++k) {        // k uniform -> scalar/broadcast load
        float4 p = pc[k];
        float dot2 = (qx * p.x + qy * p.y) + qz * p.z;   // == 2*dot, exact
        float d    = (qss + p.w) - dot2;
        if (__builtin_expect(d < d2, 0))  // no-op-equivalent guard, rare
            insert3_hit(d0, d1, d2, i0, i1, i2, d, n0 + k);
    }
    const size_t off = (size_t)c * BS + q;
    pd0[off] = d0; pd1[off] = d1; pd2[off] = d2;
    pi0[off] = i0; pi1[off] = i1; pi2[off] = i2;
}

__global__ __launch_bounds__(256)
void knn3_merge(const float* __restrict__ pd0, const float* __restrict__ pd1,
                const float* __restrict__ pd2,
                const int* __restrict__ pi0, const int* __restrict__ pi1,
                const int* __restrict__ pi2,
                int nChunk, int BS,
                int* __restrict__ idx0, int* __restrict__ idx1, int* __restrict__ idx2,
                float* __restrict__ w0, float* __restrict__ w1, float* __restrict__ w2)
{
#pragma clang fp contract(off)
    const int q = blockIdx.x * 256 + threadIdx.x;
    if (q >= BS) return;
    float d0 = 3.4e38f, d1 = 3.4e38f, d2 = 3.4e38f;
    int   i0 = 0, i1 = 0, i2 = 0;
    // ascending chunk order + strict-< insertion == top_k lowest-index ties
    for (int c = 0; c < nChunk; ++c) {
        const size_t off = (size_t)c * BS + q;
        insert3b(d0, d1, d2, i0, i1, i2, pd0[off], pi0[off]);
        insert3b(d0, d1, d2, i0, i1, i2, pd1[off], pi1[off]);
        insert3b(d0, d1, d2, i0, i1, i2, pd2[off], pi2[off]);
    }
    const float r0 = 1.0f / (d0 + 1e-8f);
    const float r1 = 1.0f / (d1 + 1e-8f);
    const float r2 = 1.0f / (d2 + 1e-8f);
    const float sum = (r0 + r1) + r2;
    idx0[q] = i0; idx1[q] = i1; idx2[q] = i2;
    w0[q] = r0 / sum; w1[q] = r1 / sum; w2[q] = r2 / sum;
}

__global__ __launch_bounds__(256)
void interp_kernel(const float* __restrict__ points1,
                   const int* __restrict__ idx0, const int* __restrict__ idx1,
                   const int* __restrict__ idx2,
                   const float* __restrict__ w0, const float* __restrict__ w1,
                   const float* __restrict__ w2,
                   float* __restrict__ out, int N, int S, int D)
{
#pragma clang fp contract(off)
    __shared__ float row[8192];
    const int bd = blockIdx.x;
    const int b  = bd / D;
    const float* __restrict__ src = points1 + (size_t)bd * N;

    for (int i = threadIdx.x * 4; i < N; i += blockDim.x * 4) {
        *reinterpret_cast<float4*>(&row[i]) =
            *reinterpret_cast<const float4*>(src + i);
    }
    __syncthreads();

    float* __restrict__ dst = out + (size_t)bd * S;
    const int qb = b * S;
    for (int s = threadIdx.x; s < S; s += blockDim.x) {
        int q = qb + s;
        float a = row[idx0[q]] * w0[q];
        float c = row[idx1[q]] * w1[q];
        float e = row[idx2[q]] * w2[q];
        dst[s] = (a + c) + e;
    }
}

extern "C" void kernel_launch(void* const* d_in, const int* in_sizes, int n_in,
                              void* d_out, int out_size, void* d_ws, size_t ws_size,
                              hipStream_t stream) {
    const float* xyz1    = (const float*)d_in[0];
    const float* xyz2    = (const float*)d_in[1];
    const float* points1 = (const float*)d_in[2];
    float* out = (float*)d_out;

    const int B = 8;
    const int N = in_sizes[0] / (3 * B);
    const int S = in_sizes[1] / (3 * B);
    const int D = in_sizes[2] / (B * N);
    const int BS = B * S;
    const int nChunk = NCHUNK;
    const int cs = N / nChunk;            // 1024

    // ws layout: pk first (16B aligned), then partials, then final idx/w.
    float4* pk  = (float4*)d_ws;
    float*  pd0 = (float*)(pk + (size_t)B * N);
    float*  pd1 = pd0 + (size_t)nChunk * BS;
    float*  pd2 = pd1 + (size_t)nChunk * BS;
    int*    pi0 = (int*)(pd2 + (size_t)nChunk * BS);
    int*    pi1 = pi0 + (size_t)nChunk * BS;
    int*    pi2 = pi1 + (size_t)nChunk * BS;
    int*    idx0 = pi2 + (size_t)nChunk * BS;
    int*    idx1 = idx0 + BS;
    int*    idx2 = idx1 + BS;
    float*  w0   = (float*)(idx2 + BS);
    float*  w1   = w0 + BS;
    float*  w2   = w1 + BS;

    pack_points<<<(B * N + 255) / 256, 256, 0, stream>>>(xyz1, pk, B, N);

    dim3 g1(BS / QT, nChunk);
    knn3_main<<<g1, 256, 0, stream>>>(pk, xyz2, B, N, S, cs, BS,
                                      pd0, pd1, pd2, pi0, pi1, pi2);

    knn3_merge<<<(BS + 255) / 256, 256, 0, stream>>>(pd0, pd1, pd2, pi0, pi1, pi2,
                                                     nChunk, BS,
                                                     idx0, idx1, idx2, w0, w1, w2);

    interp_kernel<<<B * D, 256, 0, stream>>>(points1, idx0, idx1, idx2,
                                             w0, w1, w2, out, N, S, D);
}